// Round 5
// baseline (332.177 us; speedup 1.0000x reference)
//
#include <hip/hip_runtime.h>
#include <math.h>

#define HW 16384
#define B_ 8
#define C_ 256
#define S_ 64
#define K_ 8

__device__ __forceinline__ float sigmoidf_(float z) { return 1.f / (1.f + __expf(-z)); }

// ---------------- K0: precompute iv, aiv, kconst, and Wt[c][s] = wproj[s][c] ----------------
__global__ __launch_bounds__(256) void k0_prep(const float* __restrict__ anchor,
                                               const float* __restrict__ sigma_p,
                                               const float* __restrict__ wproj,
                                               float* __restrict__ iv_g, float* __restrict__ aiv_g,
                                               float* __restrict__ kconst, float* __restrict__ Wt) {
    const int c = threadIdx.x;
    const int lane = c & 63, wid = c >> 6;
    __shared__ float red[4][8];
    float kc[8];
#pragma unroll
    for (int k = 0; k < 8; ++k) {
        float sg = sigmoidf_(sigma_p[k * C_ + c]);
        float iv = 1.f / (sg * sg);
        float a = anchor[k * C_ + c];
        iv_g[k * C_ + c] = iv;
        aiv_g[k * C_ + c] = a * iv;
        kc[k] = a * a * iv;
    }
    for (int s = 0; s < S_; ++s) Wt[c * S_ + s] = wproj[s * C_ + c];
#pragma unroll
    for (int m = 32; m; m >>= 1) {
#pragma unroll
        for (int k = 0; k < 8; ++k) kc[k] += __shfl_xor(kc[k], m, 64);
    }
    if (lane == 0) {
#pragma unroll
        for (int k = 0; k < 8; ++k) red[wid][k] = kc[k];
    }
    __syncthreads();
    if (c < 8) kconst[c] = red[0][c] + red[1][c] + red[2][c] + red[3][c];
}

// ---------------- K1a: x_proj GEMM. lane=pixel (float4, vector pipe for x);
// wave owns 16 s-rows; W via wave-uniform s_load (scalar pipe, K$-shared). ----------------
__global__ __launch_bounds__(256) void k1a_proj(const float* __restrict__ x,
                                                const float* __restrict__ Wt,
                                                const float* __restrict__ bproj,
                                                float* __restrict__ xp) {
    const int tid = threadIdx.x;
    const int lane = tid & 63;
    const int wid = __builtin_amdgcn_readfirstlane(tid >> 6);  // s-group 0..3
    const int s0 = wid * 16;
    const int b = blockIdx.y;
    const int px0 = blockIdx.x * 256 + lane * 4;

    const float* xb = x + (size_t)b * C_ * HW + px0;
    const float* wbase = Wt + s0;   // + c*64, wave-uniform

    float acc[64];
#pragma unroll
    for (int i = 0; i < 64; ++i) acc[i] = 0.f;

    float4 xv = *(const float4*)xb;
#pragma unroll 2
    for (int c = 0; c < C_; ++c) {
        const int cn = (c + 1 < C_) ? c + 1 : c;
        float4 nx = *(const float4*)(xb + (size_t)cn * HW);
        const float* wr = wbase + c * S_;   // uniform -> s_load_dwordx16
#pragma unroll
        for (int s = 0; s < 16; ++s) {
            const float w = wr[s];
            acc[s * 4 + 0] = fmaf(w, xv.x, acc[s * 4 + 0]);
            acc[s * 4 + 1] = fmaf(w, xv.y, acc[s * 4 + 1]);
            acc[s * 4 + 2] = fmaf(w, xv.z, acc[s * 4 + 2]);
            acc[s * 4 + 3] = fmaf(w, xv.w, acc[s * 4 + 3]);
        }
        xv = nx;
    }

#pragma unroll
    for (int s = 0; s < 16; ++s) {
        const float bias = bproj[s0 + s];
        float4 o;
        o.x = acc[s * 4 + 0] + bias;
        o.y = acc[s * 4 + 1] + bias;
        o.z = acc[s * 4 + 2] + bias;
        o.w = acc[s * 4 + 3] + bias;
        *(float4*)(xp + ((size_t)b * S_ + s0 + s) * HW + px0) = o;
    }
}

// ---------------- K1b: d2 -> soft (fp32) + cm, 4 px/thread (float4) ----------------
__device__ __forceinline__ void fma4_(float s, const float4& v, float4& a) {
    a.x = fmaf(s, v.x, a.x);
    a.y = fmaf(s, v.y, a.y);
    a.z = fmaf(s, v.z, a.z);
    a.w = fmaf(s, v.w, a.w);
}

__global__ __launch_bounds__(256) void k1b_soft(const float* __restrict__ x,
                                                const float* __restrict__ contour,
                                                const float* __restrict__ aiv_g,
                                                const float* __restrict__ iv_g,
                                                const float* __restrict__ kconst,
                                                float* __restrict__ cm, float* __restrict__ soft) {
    __shared__ float aivl[K_ * C_];  // 8 KB
    __shared__ float ivl[K_ * C_];   // 8 KB
    const int tid = threadIdx.x;
    const int b = blockIdx.y;
    const int n = blockIdx.x * 1024 + tid * 4;

    {
        const float4* a4 = (const float4*)aiv_g;
        const float4* i4 = (const float4*)iv_g;
        float4* al = (float4*)aivl;
        float4* il = (float4*)ivl;
        for (int i = tid; i < K_ * C_ / 4; i += 256) { al[i] = a4[i]; il[i] = i4[i]; }
    }
    __syncthreads();

    float4 q1[K_], q2[K_];
#pragma unroll
    for (int k = 0; k < K_; ++k) {
        q1[k] = make_float4(0.f, 0.f, 0.f, 0.f);
        q2[k] = make_float4(0.f, 0.f, 0.f, 0.f);
    }

    const float* xbase = x + (size_t)b * C_ * HW + n;
    float4 xv = *(const float4*)xbase;
    for (int c = 0; c < C_; ++c) {
        const int cn = (c + 1 < C_) ? c + 1 : c;
        float4 nx = *(const float4*)(xbase + (size_t)cn * HW);
        float4 x2;
        x2.x = xv.x * xv.x; x2.y = xv.y * xv.y; x2.z = xv.z * xv.z; x2.w = xv.w * xv.w;
#pragma unroll
        for (int k = 0; k < K_; ++k) {
            fma4_(aivl[k * C_ + c], xv, q1[k]);
            fma4_(ivl[k * C_ + c], x2, q2[k]);
        }
        xv = nx;
    }

    // softmax over k, per component
    float4 lg[K_];
    float4 mx = make_float4(-1e30f, -1e30f, -1e30f, -1e30f);
#pragma unroll
    for (int k = 0; k < K_; ++k) {
        const float kc = kconst[k];
        lg[k].x = -0.5f * (q2[k].x - 2.f * q1[k].x + kc);
        lg[k].y = -0.5f * (q2[k].y - 2.f * q1[k].y + kc);
        lg[k].z = -0.5f * (q2[k].z - 2.f * q1[k].z + kc);
        lg[k].w = -0.5f * (q2[k].w - 2.f * q1[k].w + kc);
        mx.x = fmaxf(mx.x, lg[k].x); mx.y = fmaxf(mx.y, lg[k].y);
        mx.z = fmaxf(mx.z, lg[k].z); mx.w = fmaxf(mx.w, lg[k].w);
    }
    float4 sm = make_float4(0.f, 0.f, 0.f, 0.f);
#pragma unroll
    for (int k = 0; k < K_; ++k) {
        lg[k].x = __expf(lg[k].x - mx.x); sm.x += lg[k].x;
        lg[k].y = __expf(lg[k].y - mx.y); sm.y += lg[k].y;
        lg[k].z = __expf(lg[k].z - mx.z); sm.z += lg[k].z;
        lg[k].w = __expf(lg[k].w - mx.w); sm.w += lg[k].w;
    }
    const float ix = 1.f / sm.x, iy = 1.f / sm.y, iz = 1.f / sm.z, iw = 1.f / sm.w;
    float* sp = soft + (size_t)b * K_ * HW + n;
#pragma unroll
    for (int k = 0; k < K_; ++k) {
        float4 o;
        o.x = lg[k].x * ix; o.y = lg[k].y * iy; o.z = lg[k].z * iz; o.w = lg[k].w * iw;
        *(float4*)(sp + (size_t)k * HW) = o;
    }

    // cm = sigmoid(c1 - c0)
    const float4 c0 = *(const float4*)(contour + (size_t)b * 2 * HW + n);
    const float4 c1 = *(const float4*)(contour + (size_t)b * 2 * HW + HW + n);
    float4 cmv;
    cmv.x = sigmoidf_(c1.x - c0.x); cmv.y = sigmoidf_(c1.y - c0.y);
    cmv.z = sigmoidf_(c1.z - c0.z); cmv.w = sigmoidf_(c1.w - c0.w);
    *(float4*)(cm + (size_t)b * HW + n) = cmv;
}

// ---------------- K2: adaptive-pool cropped bins -> x_anchor (B,64,64) ----------------
__global__ void k2_anchor(const float* __restrict__ xp, const float* __restrict__ cm,
                          float* __restrict__ xa) {
    __shared__ float col[128];
    const int i = blockIdx.x;
    const int s = blockIdx.y;
    const int b = blockIdx.z;
    const int w = threadIdx.x;
    const int h0 = ((i + 1) * 128) / 10;
    const int h1 = ((i + 2) * 128 + 9) / 10;
    const float* xps = xp + ((size_t)b * S_ + s) * HW;
    const float* cmb = cm + (size_t)b * HW;
    float v = 0.f;
    for (int h = h0; h < h1; ++h) v += xps[h * 128 + w] * cmb[h * 128 + w];
    col[w] = v;
    __syncthreads();
    if (w < 8) {
        const int j = w;
        const int w0 = ((j + 1) * 128) / 10;
        const int w1 = ((j + 2) * 128 + 9) / 10;
        float sum = 0.f;
        for (int t = w0; t < w1; ++t) sum += col[t];
        xa[((size_t)b * S_ + s) * 64 + i * 8 + j] = sum / (float)((h1 - h0) * (w1 - w0));
    }
}

// ---------------- K3: proj = softmax_m( x_anchor^T . x_proj ), in place ----------------
__global__ __launch_bounds__(256) void k3_proj(const float* __restrict__ xa, float* __restrict__ xp) {
    const int b = blockIdx.y, tid = threadIdx.x;
    const int n = blockIdx.x * 256 + tid;
    const float* xab = xa + (size_t)b * 4096;
    float p[64];
#pragma unroll
    for (int m = 0; m < 64; ++m) p[m] = 0.f;
    float* xpb = xp + (size_t)b * S_ * HW + n;
    float xv = xpb[0];
    for (int s = 0; s < 64; ++s) {
        float xnext = (s < 63) ? xpb[(size_t)(s + 1) * HW] : 0.f;
#pragma unroll
        for (int m = 0; m < 64; m += 4) {
            const float4 a = *(const float4*)&xab[s * 64 + m];
            p[m] = fmaf(a.x, xv, p[m]);
            p[m + 1] = fmaf(a.y, xv, p[m + 1]);
            p[m + 2] = fmaf(a.z, xv, p[m + 2]);
            p[m + 3] = fmaf(a.w, xv, p[m + 3]);
        }
        xv = xnext;
    }
    float mx = -1e30f;
#pragma unroll
    for (int m = 0; m < 64; ++m) mx = fmaxf(mx, p[m]);
    float sm = 0.f;
#pragma unroll
    for (int m = 0; m < 64; ++m) { float e = __expf(p[m] - mx); p[m] = e; sm += e; }
    float inv = 1.f / sm;
#pragma unroll
    for (int m = 0; m < 64; ++m) xpb[(size_t)m * HW] = p[m] * inv;
}

// ---------------- K4: ssum[b,k] = sum_n soft[b,k,n] ----------------
__global__ __launch_bounds__(256) void k4_ssum(const float* __restrict__ soft,
                                               float* __restrict__ ssumg) {
    const int bk = blockIdx.x;
    const int tid = threadIdx.x;
    const float4* sp = (const float4*)(soft + (size_t)bk * HW);
    float v = 0.f;
    for (int i = tid; i < HW / 4; i += 256) {
        float4 t = sp[i];
        v += (t.x + t.y) + (t.z + t.w);
    }
#pragma unroll
    for (int m = 32; m; m >>= 1) v += __shfl_xor(v, m, 64);
    __shared__ float red[4];
    const int wid = tid >> 6, lane = tid & 63;
    if (lane == 0) red[wid] = v;
    __syncthreads();
    if (tid == 0) ssumg[bk] = red[0] + red[1] + red[2] + red[3];
}

// ---------------- K5: wsum[b,k,c] = sum_n soft[b,k,n] * x[b,c,n] (float4) ----------------
__global__ __launch_bounds__(256) void k5_wsum(const float* __restrict__ x,
                                               const float* __restrict__ soft,
                                               float* __restrict__ wsum) {
    const int b = blockIdx.y;
    const int c0 = blockIdx.x * 4;
    const int tid = threadIdx.x;
    float a[32];
#pragma unroll
    for (int i = 0; i < 32; ++i) a[i] = 0.f;
    const float4* sb = (const float4*)(soft + (size_t)b * K_ * HW);
    const float4* xb = (const float4*)(x + ((size_t)b * C_ + c0) * HW);
    for (int i = tid; i < HW / 4; i += 256) {
        float4 sv[8];
#pragma unroll
        for (int k = 0; k < 8; ++k) sv[k] = sb[(size_t)k * (HW / 4) + i];
#pragma unroll
        for (int ci = 0; ci < 4; ++ci) {
            float4 xv = xb[(size_t)ci * (HW / 4) + i];
#pragma unroll
            for (int k = 0; k < 8; ++k) {
                float t = fmaf(sv[k].x, xv.x, fmaf(sv[k].y, xv.y,
                          fmaf(sv[k].z, xv.z, sv[k].w * xv.w)));
                a[ci * 8 + k] += t;
            }
        }
    }
    __shared__ float red[128];
    const int lane = tid & 63, wid = tid >> 6;
#pragma unroll
    for (int o = 0; o < 32; ++o) {
        float v = a[o];
#pragma unroll
        for (int m = 32; m; m >>= 1) v += __shfl_xor(v, m, 64);
        if (lane == 0) red[wid * 32 + o] = v;
    }
    __syncthreads();
    if (tid < 32) {
        float r = red[tid] + red[32 + tid] + red[64 + tid] + red[96 + tid];
        int ci = tid >> 3, k = tid & 7;
        wsum[((size_t)b * K_ + k) * C_ + c0 + ci] = r;
    }
}

// ---------------- K6: nodes, normalize, 3x GCN, relu -> g ----------------
__device__ __forceinline__ float blockSum256(float v, volatile float* sc) {
#pragma unroll
    for (int m = 32; m; m >>= 1) v += __shfl_xor(v, m, 64);
    const int wid = threadIdx.x >> 6, lane = threadIdx.x & 63;
    __syncthreads();
    if (lane == 0) sc[wid] = v;
    __syncthreads();
    return sc[0] + sc[1] + sc[2] + sc[3];
}

__global__ __launch_bounds__(256) void k6_gcn(const float* __restrict__ ssumg,
                                              const float* __restrict__ wsum,
                                              const float* __restrict__ anchor,
                                              const float* __restrict__ sigma_p,
                                              const float* __restrict__ w1,
                                              const float* __restrict__ w2,
                                              const float* __restrict__ w3,
                                              float* __restrict__ gout) {
    const int b = blockIdx.x;
    const int tid = threadIdx.x;
    const int lane = tid & 63, wid = tid >> 6;
    __shared__ float g_lds[2048];
    __shared__ float A[64];
    __shared__ float sc[4];
    __shared__ float red8[4][8];
    __shared__ float ssk_s[8];

    if (tid < 8) ssk_s[tid] = ssumg[b * 8 + tid];
    __syncthreads();
    float ssk[8];
#pragma unroll
    for (int k = 0; k < 8; ++k) ssk[k] = ssk_s[k];

    const int c = tid;
    float node[8];
#pragma unroll
    for (int k = 0; k < 8; ++k) {
        float sg = sigmoidf_(sigma_p[k * C_ + c]);
        float w = wsum[((size_t)b * K_ + k) * C_ + c];
        node[k] = (w - anchor[k * C_ + c] * ssk[k]) / sg / (ssk[k] + 1e-9f);
    }
    float rn[8];
#pragma unroll
    for (int k = 0; k < 8; ++k) rn[k] = node[k] * node[k];
#pragma unroll
    for (int m = 32; m; m >>= 1) {
#pragma unroll
        for (int k = 0; k < 8; ++k) rn[k] += __shfl_xor(rn[k], m, 64);
    }
    if (lane == 0) {
#pragma unroll
        for (int k = 0; k < 8; ++k) red8[wid][k] = rn[k];
    }
    __syncthreads();
#pragma unroll
    for (int k = 0; k < 8; ++k) {
        float t = red8[0][k] + red8[1][k] + red8[2][k] + red8[3][k];
        node[k] /= fmaxf(sqrtf(t), 1e-12f);
    }
    float fs = 0.f;
#pragma unroll
    for (int k = 0; k < 8; ++k) fs += node[k] * node[k];
    float fn = blockSum256(fs, sc);
    float finv = 1.f / fmaxf(sqrtf(fn), 1e-12f);
#pragma unroll
    for (int k = 0; k < 8; ++k) g_lds[tid * 8 + k] = node[k] * finv;
    __syncthreads();

    const float* Ws[3] = {w1, w2, w3};
    for (int L = 0; L < 3; ++L) {
        {
            const int pair = tid >> 2, part = tid & 3;
            const int p = pair >> 3, q = pair & 7;
            float s = 0.f;
            for (int i = part * 64; i < part * 64 + 64; ++i)
                s += g_lds[i * 8 + p] * g_lds[i * 8 + q];
            s += __shfl_xor(s, 1, 64);
            s += __shfl_xor(s, 2, 64);
            if (part == 0) A[pair] = s;
        }
        __syncthreads();
        if (tid < 8) {
            float mx = -1e30f;
            for (int j = 0; j < 8; ++j) mx = fmaxf(mx, A[tid * 8 + j]);
            float sm = 0.f;
            for (int j = 0; j < 8; ++j) { float e = __expf(A[tid * 8 + j] - mx); A[tid * 8 + j] = e; sm += e; }
            float iv = 1.f / sm;
            for (int j = 0; j < 8; ++j) A[tid * 8 + j] *= iv;
        }
        __syncthreads();
        float sup[8];
#pragma unroll
        for (int j = 0; j < 8; ++j) sup[j] = 0.f;
        const float* W = Ws[L];
        float wv[8], wn[8];
#pragma unroll
        for (int i = 0; i < 8; ++i) wv[i] = W[(size_t)i * 256 + tid];
        for (int c0 = 0; c0 < 256; c0 += 8) {
            if (c0 + 8 < 256) {
#pragma unroll
                for (int i = 0; i < 8; ++i) wn[i] = W[(size_t)(c0 + 8 + i) * 256 + tid];
            }
#pragma unroll
            for (int i = 0; i < 8; ++i) {
#pragma unroll
                for (int j = 0; j < 8; ++j)
                    sup[j] = fmaf(g_lds[(c0 + i) * 8 + j], wv[i], sup[j]);
            }
#pragma unroll
            for (int i = 0; i < 8; ++i) wv[i] = wn[i];
        }
        float gn[8];
#pragma unroll
        for (int k = 0; k < 8; ++k) {
            float s = 0.f;
#pragma unroll
            for (int j = 0; j < 8; ++j) s += A[k * 8 + j] * sup[j];
            gn[k] = s;
        }
        __syncthreads();
#pragma unroll
        for (int k = 0; k < 8; ++k) g_lds[tid * 8 + k] = gn[k];
        __syncthreads();
    }
#pragma unroll
    for (int k = 0; k < 8; ++k)
        gout[(size_t)b * 2048 + tid * 8 + k] = fmaxf(g_lds[tid * 8 + k], 0.f);
}

extern "C" void kernel_launch(void* const* d_in, const int* in_sizes, int n_in,
                              void* d_out, int out_size, void* d_ws, size_t ws_size,
                              hipStream_t stream) {
    const float* x = (const float*)d_in[0];
    const float* contour = (const float*)d_in[1];
    const float* wproj = (const float*)d_in[4];
    const float* bproj = (const float*)d_in[5];
    const float* anchor = (const float*)d_in[6];
    const float* sigma_p = (const float*)d_in[7];
    const float* w1 = (const float*)d_in[8];
    const float* w2 = (const float*)d_in[9];
    const float* w3 = (const float*)d_in[10];

    float* out = (float*)d_out;
    float* g_out = out;                        // (B,256,8)
    float* xp = out + 16384;                   // proj region (B,64,HW)
    float* soft = out + 16384 + 8388608;       // (B,8,HW)

    float* ws = (float*)d_ws;
    float* cm = ws;                 // B*HW = 131072
    float* xa = ws + 131072;        // 32768
    float* wsum = ws + 163840;      // 16384
    float* kconst = ws + 180224;    // 8
    float* ssumg = ws + 180232;     // 64
    float* iv_g = ws + 180296;      // 2048
    float* aiv_g = ws + 182344;     // 2048
    float* Wt = ws + 184392;        // 16384

    k0_prep<<<1, 256, 0, stream>>>(anchor, sigma_p, wproj, iv_g, aiv_g, kconst, Wt);
    k1a_proj<<<dim3(HW / 256, B_), 256, 0, stream>>>(x, Wt, bproj, xp);
    k1b_soft<<<dim3(HW / 1024, B_), 256, 0, stream>>>(x, contour, aiv_g, iv_g, kconst, cm, soft);
    k4_ssum<<<B_ * K_, 256, 0, stream>>>(soft, ssumg);
    k2_anchor<<<dim3(8, 64, B_), 128, 0, stream>>>(xp, cm, xa);
    k3_proj<<<dim3(64, B_), 256, 0, stream>>>(xa, xp);
    k5_wsum<<<dim3(64, B_), 256, 0, stream>>>(x, soft, wsum);
    k6_gcn<<<B_, 256, 0, stream>>>(ssumg, wsum, anchor, sigma_p, w1, w2, w3, g_out);
}

// Round 6
// 297.915 us; speedup vs baseline: 1.1150x; 1.1150x over previous
//
#include <hip/hip_runtime.h>
#include <math.h>

#define HW 16384
#define B_ 8
#define C_ 256
#define S_ 64
#define K_ 8

__device__ __forceinline__ float sigmoidf_(float z) { return 1.f / (1.f + __expf(-z)); }

// ---------------- K0: precompute Wt[c][s], ivaiv[c][0..7]=aiv,[8..15]=iv, kconst ----------------
__global__ __launch_bounds__(256) void k0_prep(const float* __restrict__ anchor,
                                               const float* __restrict__ sigma_p,
                                               const float* __restrict__ wproj,
                                               float* __restrict__ Wt, float* __restrict__ ivaiv,
                                               float* __restrict__ kconst) {
    const int c = threadIdx.x;
    const int lane = c & 63, wid = c >> 6;
    __shared__ float red[4][8];
    float kc[8];
#pragma unroll
    for (int k = 0; k < 8; ++k) {
        float sg = sigmoidf_(sigma_p[k * C_ + c]);
        float iv = 1.f / (sg * sg);
        float a = anchor[k * C_ + c];
        ivaiv[c * 16 + k] = a * iv;
        ivaiv[c * 16 + 8 + k] = iv;
        kc[k] = a * a * iv;
    }
    for (int s = 0; s < S_; ++s) Wt[c * S_ + s] = wproj[s * C_ + c];
#pragma unroll
    for (int m = 32; m; m >>= 1) {
#pragma unroll
        for (int k = 0; k < 8; ++k) kc[k] += __shfl_xor(kc[k], m, 64);
    }
    if (lane == 0) {
#pragma unroll
        for (int k = 0; k < 8; ++k) red[wid][k] = kc[k];
    }
    __syncthreads();
    if (c < 8) kconst[c] = red[0][c] + red[1][c] + red[2][c] + red[3][c];
}

// ---------------- K1 fused: x_proj + soft + cm. lane = pixel; wave = 64 distinct px.
// x: vector pipe (1 dword/lane/step, 4-deep pipeline). W + aiv/iv: scalar pipe (s_load). ----------------
__global__ __launch_bounds__(256) void k1_fused(
    const float* __restrict__ x, const float* __restrict__ contour,
    const float* __restrict__ Wt, const float* __restrict__ bproj,
    const float* __restrict__ ivaiv, const float* __restrict__ kconst,
    float* __restrict__ cm, float* __restrict__ xp, float* __restrict__ soft) {
    const int tid = threadIdx.x;
    const int b = blockIdx.y;
    const int px = blockIdx.x * 256 + tid;   // lane-contiguous pixel

    const float* xb = x + (size_t)b * C_ * HW + px;

    float acc[S_];
#pragma unroll
    for (int s = 0; s < S_; ++s) acc[s] = 0.f;
    float q1[K_], q2[K_];
#pragma unroll
    for (int k = 0; k < K_; ++k) { q1[k] = 0.f; q2[k] = 0.f; }

    // 4-deep software pipeline over channels (named regs; no runtime-indexed arrays)
    float a0 = xb[0], a1 = xb[(size_t)1 * HW], a2 = xb[(size_t)2 * HW], a3 = xb[(size_t)3 * HW];

#define BODY(REG, CC, CN)                                                        \
    {                                                                            \
        const float xv = REG;                                                    \
        if ((CN) < C_) REG = xb[(size_t)(CN) * HW];                              \
        const float* wr = Wt + (CC) * S_;        /* uniform -> s_load x16 */     \
        _Pragma("unroll")                                                        \
        for (int s = 0; s < S_; ++s) acc[s] = fmaf(wr[s], xv, acc[s]);           \
        const float* t = ivaiv + (CC) * 16;      /* uniform -> s_load x16 */     \
        const float x2 = xv * xv;                                                \
        _Pragma("unroll")                                                        \
        for (int k = 0; k < K_; ++k) {                                           \
            q1[k] = fmaf(t[k], xv, q1[k]);                                       \
            q2[k] = fmaf(t[8 + k], x2, q2[k]);                                   \
        }                                                                        \
    }

    for (int c = 0; c < C_; c += 4) {
        BODY(a0, c + 0, c + 4)
        BODY(a1, c + 1, c + 5)
        BODY(a2, c + 2, c + 6)
        BODY(a3, c + 3, c + 7)
    }
#undef BODY

    // x_proj writes (coalesced dword per s-row)
    float* xpb = xp + (size_t)b * S_ * HW + px;
#pragma unroll
    for (int s = 0; s < S_; ++s) xpb[(size_t)s * HW] = acc[s] + bproj[s];

    // soft = softmax_k(-0.5 * (q2 - 2 q1 + kconst))
    float lg[K_], mx = -1e30f;
#pragma unroll
    for (int k = 0; k < K_; ++k) {
        lg[k] = -0.5f * (q2[k] - 2.f * q1[k] + kconst[k]);
        mx = fmaxf(mx, lg[k]);
    }
    float sm = 0.f;
#pragma unroll
    for (int k = 0; k < K_; ++k) { float e = __expf(lg[k] - mx); lg[k] = e; sm += e; }
    const float inv = 1.f / sm;
    float* sp = soft + (size_t)b * K_ * HW + px;
#pragma unroll
    for (int k = 0; k < K_; ++k) sp[(size_t)k * HW] = lg[k] * inv;

    // cm = sigmoid(c1 - c0)
    const float c0v = contour[(size_t)b * 2 * HW + px];
    const float c1v = contour[(size_t)b * 2 * HW + HW + px];
    cm[(size_t)b * HW + px] = sigmoidf_(c1v - c0v);
}

// ---------------- K2: adaptive-pool cropped bins -> x_anchor (B,64,64) ----------------
__global__ void k2_anchor(const float* __restrict__ xp, const float* __restrict__ cm,
                          float* __restrict__ xa) {
    __shared__ float col[128];
    const int i = blockIdx.x;
    const int s = blockIdx.y;
    const int b = blockIdx.z;
    const int w = threadIdx.x;
    const int h0 = ((i + 1) * 128) / 10;
    const int h1 = ((i + 2) * 128 + 9) / 10;
    const float* xps = xp + ((size_t)b * S_ + s) * HW;
    const float* cmb = cm + (size_t)b * HW;
    float v = 0.f;
    for (int h = h0; h < h1; ++h) v += xps[h * 128 + w] * cmb[h * 128 + w];
    col[w] = v;
    __syncthreads();
    if (w < 8) {
        const int j = w;
        const int w0 = ((j + 1) * 128) / 10;
        const int w1 = ((j + 2) * 128 + 9) / 10;
        float sum = 0.f;
        for (int t = w0; t < w1; ++t) sum += col[t];
        xa[((size_t)b * S_ + s) * 64 + i * 8 + j] = sum / (float)((h1 - h0) * (w1 - w0));
    }
}

// ---------------- K3: proj = softmax_m( x_anchor^T . x_proj ), in place ----------------
__global__ __launch_bounds__(256) void k3_proj(const float* __restrict__ xa, float* __restrict__ xp) {
    const int b = blockIdx.y, tid = threadIdx.x;
    const int n = blockIdx.x * 256 + tid;
    const float* xab = xa + (size_t)b * 4096;
    float p[64];
#pragma unroll
    for (int m = 0; m < 64; ++m) p[m] = 0.f;
    float* xpb = xp + (size_t)b * S_ * HW + n;
    float xv = xpb[0];
    for (int s = 0; s < 64; ++s) {
        float xnext = (s < 63) ? xpb[(size_t)(s + 1) * HW] : 0.f;
#pragma unroll
        for (int m = 0; m < 64; m += 4) {
            const float4 a = *(const float4*)&xab[s * 64 + m];
            p[m] = fmaf(a.x, xv, p[m]);
            p[m + 1] = fmaf(a.y, xv, p[m + 1]);
            p[m + 2] = fmaf(a.z, xv, p[m + 2]);
            p[m + 3] = fmaf(a.w, xv, p[m + 3]);
        }
        xv = xnext;
    }
    float mx = -1e30f;
#pragma unroll
    for (int m = 0; m < 64; ++m) mx = fmaxf(mx, p[m]);
    float sm = 0.f;
#pragma unroll
    for (int m = 0; m < 64; ++m) { float e = __expf(p[m] - mx); p[m] = e; sm += e; }
    float inv = 1.f / sm;
#pragma unroll
    for (int m = 0; m < 64; ++m) xpb[(size_t)m * HW] = p[m] * inv;
}

// ---------------- K4: ssum[b,k] = sum_n soft[b,k,n] ----------------
__global__ __launch_bounds__(256) void k4_ssum(const float* __restrict__ soft,
                                               float* __restrict__ ssumg) {
    const int bk = blockIdx.x;
    const int tid = threadIdx.x;
    const float4* sp = (const float4*)(soft + (size_t)bk * HW);
    float v = 0.f;
    for (int i = tid; i < HW / 4; i += 256) {
        float4 t = sp[i];
        v += (t.x + t.y) + (t.z + t.w);
    }
#pragma unroll
    for (int m = 32; m; m >>= 1) v += __shfl_xor(v, m, 64);
    __shared__ float red[4];
    const int wid = tid >> 6, lane = tid & 63;
    if (lane == 0) red[wid] = v;
    __syncthreads();
    if (tid == 0) ssumg[bk] = red[0] + red[1] + red[2] + red[3];
}

// ---------------- K5: wsum[b,k,c] = sum_n soft[b,k,n] * x[b,c,n] (float4) ----------------
__global__ __launch_bounds__(256) void k5_wsum(const float* __restrict__ x,
                                               const float* __restrict__ soft,
                                               float* __restrict__ wsum) {
    const int b = blockIdx.y;
    const int c0 = blockIdx.x * 4;
    const int tid = threadIdx.x;
    float a[32];
#pragma unroll
    for (int i = 0; i < 32; ++i) a[i] = 0.f;
    const float4* sb = (const float4*)(soft + (size_t)b * K_ * HW);
    const float4* xb = (const float4*)(x + ((size_t)b * C_ + c0) * HW);
    for (int i = tid; i < HW / 4; i += 256) {
        float4 sv[8];
#pragma unroll
        for (int k = 0; k < 8; ++k) sv[k] = sb[(size_t)k * (HW / 4) + i];
#pragma unroll
        for (int ci = 0; ci < 4; ++ci) {
            float4 xv = xb[(size_t)ci * (HW / 4) + i];
#pragma unroll
            for (int k = 0; k < 8; ++k) {
                float t = fmaf(sv[k].x, xv.x, fmaf(sv[k].y, xv.y,
                          fmaf(sv[k].z, xv.z, sv[k].w * xv.w)));
                a[ci * 8 + k] += t;
            }
        }
    }
    __shared__ float red[128];
    const int lane = tid & 63, wid = tid >> 6;
#pragma unroll
    for (int o = 0; o < 32; ++o) {
        float v = a[o];
#pragma unroll
        for (int m = 32; m; m >>= 1) v += __shfl_xor(v, m, 64);
        if (lane == 0) red[wid * 32 + o] = v;
    }
    __syncthreads();
    if (tid < 32) {
        float r = red[tid] + red[32 + tid] + red[64 + tid] + red[96 + tid];
        int ci = tid >> 3, k = tid & 7;
        wsum[((size_t)b * K_ + k) * C_ + c0 + ci] = r;
    }
}

// ---------------- K6: nodes, normalize, 3x GCN, relu -> g ----------------
__device__ __forceinline__ float blockSum256(float v, volatile float* sc) {
#pragma unroll
    for (int m = 32; m; m >>= 1) v += __shfl_xor(v, m, 64);
    const int wid = threadIdx.x >> 6, lane = threadIdx.x & 63;
    __syncthreads();
    if (lane == 0) sc[wid] = v;
    __syncthreads();
    return sc[0] + sc[1] + sc[2] + sc[3];
}

__global__ __launch_bounds__(256) void k6_gcn(const float* __restrict__ ssumg,
                                              const float* __restrict__ wsum,
                                              const float* __restrict__ anchor,
                                              const float* __restrict__ sigma_p,
                                              const float* __restrict__ w1,
                                              const float* __restrict__ w2,
                                              const float* __restrict__ w3,
                                              float* __restrict__ gout) {
    const int b = blockIdx.x;
    const int tid = threadIdx.x;
    const int lane = tid & 63, wid = tid >> 6;
    __shared__ float g_lds[2048];
    __shared__ float A[64];
    __shared__ float sc[4];
    __shared__ float red8[4][8];
    __shared__ float ssk_s[8];

    if (tid < 8) ssk_s[tid] = ssumg[b * 8 + tid];
    __syncthreads();
    float ssk[8];
#pragma unroll
    for (int k = 0; k < 8; ++k) ssk[k] = ssk_s[k];

    const int c = tid;
    float node[8];
#pragma unroll
    for (int k = 0; k < 8; ++k) {
        float sg = sigmoidf_(sigma_p[k * C_ + c]);
        float w = wsum[((size_t)b * K_ + k) * C_ + c];
        node[k] = (w - anchor[k * C_ + c] * ssk[k]) / sg / (ssk[k] + 1e-9f);
    }
    float rn[8];
#pragma unroll
    for (int k = 0; k < 8; ++k) rn[k] = node[k] * node[k];
#pragma unroll
    for (int m = 32; m; m >>= 1) {
#pragma unroll
        for (int k = 0; k < 8; ++k) rn[k] += __shfl_xor(rn[k], m, 64);
    }
    if (lane == 0) {
#pragma unroll
        for (int k = 0; k < 8; ++k) red8[wid][k] = rn[k];
    }
    __syncthreads();
#pragma unroll
    for (int k = 0; k < 8; ++k) {
        float t = red8[0][k] + red8[1][k] + red8[2][k] + red8[3][k];
        node[k] /= fmaxf(sqrtf(t), 1e-12f);
    }
    float fs = 0.f;
#pragma unroll
    for (int k = 0; k < 8; ++k) fs += node[k] * node[k];
    float fn = blockSum256(fs, sc);
    float finv = 1.f / fmaxf(sqrtf(fn), 1e-12f);
#pragma unroll
    for (int k = 0; k < 8; ++k) g_lds[tid * 8 + k] = node[k] * finv;
    __syncthreads();

    const float* Ws[3] = {w1, w2, w3};
    for (int L = 0; L < 3; ++L) {
        {
            const int pair = tid >> 2, part = tid & 3;
            const int p = pair >> 3, q = pair & 7;
            float s = 0.f;
            for (int i = part * 64; i < part * 64 + 64; ++i)
                s += g_lds[i * 8 + p] * g_lds[i * 8 + q];
            s += __shfl_xor(s, 1, 64);
            s += __shfl_xor(s, 2, 64);
            if (part == 0) A[pair] = s;
        }
        __syncthreads();
        if (tid < 8) {
            float mx = -1e30f;
            for (int j = 0; j < 8; ++j) mx = fmaxf(mx, A[tid * 8 + j]);
            float sm = 0.f;
            for (int j = 0; j < 8; ++j) { float e = __expf(A[tid * 8 + j] - mx); A[tid * 8 + j] = e; sm += e; }
            float iv = 1.f / sm;
            for (int j = 0; j < 8; ++j) A[tid * 8 + j] *= iv;
        }
        __syncthreads();
        float sup[8];
#pragma unroll
        for (int j = 0; j < 8; ++j) sup[j] = 0.f;
        const float* W = Ws[L];
        float wv[8], wn[8];
#pragma unroll
        for (int i = 0; i < 8; ++i) wv[i] = W[(size_t)i * 256 + tid];
        for (int c0 = 0; c0 < 256; c0 += 8) {
            if (c0 + 8 < 256) {
#pragma unroll
                for (int i = 0; i < 8; ++i) wn[i] = W[(size_t)(c0 + 8 + i) * 256 + tid];
            }
#pragma unroll
            for (int i = 0; i < 8; ++i) {
#pragma unroll
                for (int j = 0; j < 8; ++j)
                    sup[j] = fmaf(g_lds[(c0 + i) * 8 + j], wv[i], sup[j]);
            }
#pragma unroll
            for (int i = 0; i < 8; ++i) wv[i] = wn[i];
        }
        float gn[8];
#pragma unroll
        for (int k = 0; k < 8; ++k) {
            float s = 0.f;
#pragma unroll
            for (int j = 0; j < 8; ++j) s += A[k * 8 + j] * sup[j];
            gn[k] = s;
        }
        __syncthreads();
#pragma unroll
        for (int k = 0; k < 8; ++k) g_lds[tid * 8 + k] = gn[k];
        __syncthreads();
    }
#pragma unroll
    for (int k = 0; k < 8; ++k)
        gout[(size_t)b * 2048 + tid * 8 + k] = fmaxf(g_lds[tid * 8 + k], 0.f);
}

extern "C" void kernel_launch(void* const* d_in, const int* in_sizes, int n_in,
                              void* d_out, int out_size, void* d_ws, size_t ws_size,
                              hipStream_t stream) {
    const float* x = (const float*)d_in[0];
    const float* contour = (const float*)d_in[1];
    const float* wproj = (const float*)d_in[4];
    const float* bproj = (const float*)d_in[5];
    const float* anchor = (const float*)d_in[6];
    const float* sigma_p = (const float*)d_in[7];
    const float* w1 = (const float*)d_in[8];
    const float* w2 = (const float*)d_in[9];
    const float* w3 = (const float*)d_in[10];

    float* out = (float*)d_out;
    float* g_out = out;                        // (B,256,8)
    float* xp = out + 16384;                   // proj region (B,64,HW)
    float* soft = out + 16384 + 8388608;       // (B,8,HW)

    float* ws = (float*)d_ws;
    float* cm = ws;                 // B*HW = 131072
    float* xa = ws + 131072;        // 32768
    float* wsum = ws + 163840;      // 16384
    float* kconst = ws + 180224;    // 8
    float* ssumg = ws + 180232;     // 64
    float* Wt = ws + 180296;        // 16384
    float* ivaiv = ws + 196680;     // 4096

    k0_prep<<<1, 256, 0, stream>>>(anchor, sigma_p, wproj, Wt, ivaiv, kconst);
    k1_fused<<<dim3(HW / 256, B_), 256, 0, stream>>>(x, contour, Wt, bproj, ivaiv, kconst,
                                                     cm, xp, soft);
    k4_ssum<<<B_ * K_, 256, 0, stream>>>(soft, ssumg);
    k2_anchor<<<dim3(8, 64, B_), 128, 0, stream>>>(xp, cm, xa);
    k3_proj<<<dim3(64, B_), 256, 0, stream>>>(xa, xp);
    k5_wsum<<<dim3(64, B_), 256, 0, stream>>>(x, soft, wsum);
    k6_gcn<<<B_, 256, 0, stream>>>(ssumg, wsum, anchor, sigma_p, w1, w2, w3, g_out);
}